// Round 2
// baseline (581.679 us; speedup 1.0000x reference)
//
#include <hip/hip_runtime.h>
#include <hip/hip_bf16.h>

#define HDD 64
#define NH 16
#define SEQ 2048
#define DM 1024
#define BB 4

using bf16x8 = __attribute__((ext_vector_type(8))) short;
using floatx4 = __attribute__((ext_vector_type(4))) float;
typedef unsigned int u32;

__device__ __forceinline__ short f2bf(float f) {
    __hip_bfloat16 h = __float2bfloat16(f);
    union { __hip_bfloat16 h; short s; } c;
    c.h = h;
    return c.s;
}

// Stage 8 contiguous fp32 elements from global into LDS as bf16.
__device__ __forceinline__ void stage8f(short* dst, const float* s) {
    float4 a = *(const float4*)s;
    float4 b = *(const float4*)(s + 4);
    bf16x8 r;
    r[0] = f2bf(a.x); r[1] = f2bf(a.y); r[2] = f2bf(a.z); r[3] = f2bf(a.w);
    r[4] = f2bf(b.x); r[5] = f2bf(b.y); r[6] = f2bf(b.z); r[7] = f2bf(b.w);
    *(bf16x8*)dst = r;
}

// ---------------------------------------------------------------------------
// QKV projection: Y = X @ W^T + b (fp32 in, bf16 MFMA), written head-split
// as [B,H,S,HD] bf16 into ws. For Q (z==0), 0.125*log2(e) is folded in so
// the attention kernel can use exp2 on unscaled MFMA scores.
// ---------------------------------------------------------------------------
__global__ __launch_bounds__(256) void proj_kernel(
    const float* __restrict__ q, const float* __restrict__ k, const float* __restrict__ v,
    const float* __restrict__ wq, const float* __restrict__ bq,
    const float* __restrict__ wk, const float* __restrict__ bk,
    const float* __restrict__ wv, const float* __restrict__ bv,
    short* __restrict__ Qh, short* __restrict__ Kh, short* __restrict__ Vh)
{
    const int z = blockIdx.z;
    const float* X  = (z == 0) ? q  : (z == 1) ? k  : v;
    const float* W  = (z == 0) ? wq : (z == 1) ? wk : wv;
    const float* Bp = (z == 0) ? bq : (z == 1) ? bk : bv;
    short* Dst      = (z == 0) ? Qh : (z == 1) ? Kh : Vh;
    const float qscale = (z == 0) ? (0.125f * 1.44269504088896f) : 1.0f;

    const int m0 = blockIdx.x * 128;
    const int n0 = blockIdx.y * 128;
    const int tid = threadIdx.x;
    const int w = tid >> 6, lane = tid & 63, lc = lane & 15, lq = lane >> 4;
    const int wm = w >> 1, wn = w & 1;

    __shared__ alignas(16) short As[128 * 40];
    __shared__ alignas(16) short Bs[128 * 40];

    floatx4 acc[4][4];
#pragma unroll
    for (int i = 0; i < 4; i++)
#pragma unroll
        for (int j = 0; j < 4; j++) acc[i][j] = floatx4{0.f, 0.f, 0.f, 0.f};

    for (int kt = 0; kt < DM / 32; ++kt) {
        __syncthreads();
#pragma unroll
        for (int c = 0; c < 2; ++c) {
            int chunk = c * 256 + tid;
            int row = chunk >> 2;
            int col = (chunk & 3) * 8;
            stage8f(As + row * 40 + col, X + (size_t)(m0 + row) * DM + kt * 32 + col);
            stage8f(Bs + row * 40 + col, W + (size_t)(n0 + row) * DM + kt * 32 + col);
        }
        __syncthreads();

        bf16x8 aF[4], bF[4];
#pragma unroll
        for (int i = 0; i < 4; i++)
            aF[i] = *(const bf16x8*)(As + (wm * 64 + i * 16 + lc) * 40 + lq * 8);
#pragma unroll
        for (int j = 0; j < 4; j++)
            bF[j] = *(const bf16x8*)(Bs + (wn * 64 + j * 16 + lc) * 40 + lq * 8);
        __builtin_amdgcn_s_setprio(1);
#pragma unroll
        for (int i = 0; i < 4; i++)
#pragma unroll
            for (int j = 0; j < 4; j++)
                acc[i][j] = __builtin_amdgcn_mfma_f32_16x16x32_bf16(aF[i], bF[j], acc[i][j], 0, 0, 0);
        __builtin_amdgcn_s_setprio(0);
    }

#pragma unroll
    for (int j = 0; j < 4; j++) {
        int n = n0 + wn * 64 + j * 16 + lc;
        float bias = Bp[n];
        int h = n >> 6, hd = n & 63;
#pragma unroll
        for (int i = 0; i < 4; i++) {
#pragma unroll
            for (int r = 0; r < 4; r++) {
                int m = m0 + wm * 64 + i * 16 + lq * 4 + r;
                int b = m >> 11, s = m & 2047;
                float val = (acc[i][j][r] + bias) * qscale;
                Dst[(((size_t)(b * NH + h)) * SEQ + s) * HDD + hd] = f2bf(val);
            }
        }
    }
}

// ---------------------------------------------------------------------------
// Flash attention, swapped-operand QK^T:
//   S^T = mfma(A=K, B=Q)  ->  lane (lc,lq) holds S^T[kv=nt*16+lq*4+r][q=lc]
// Each lane owns ONE q-row (q = lc): softmax reduce = in-lane + 2 shfl_xor.
// P stays in registers; repacked to the PV operand layout via shuffles.
// PV computes O^T = mfma(A=V^T, B=P^T); V^T staged in XOR-swizzled,
// double-buffered LDS with one barrier per tile and early-issued loads.
// ---------------------------------------------------------------------------
__global__ __launch_bounds__(256) void attn_kernel(
    const short* __restrict__ Qh, const short* __restrict__ Kh,
    const short* __restrict__ Vh, float* __restrict__ ctxout)
{
    // XCD-aware swizzle: 2048 blocks / 8 XCDs -> each XCD owns 8 consecutive
    // (b,h) pairs; its K/V working set = 8 * 512KB = 4MB = one XCD L2.
    const int linear = blockIdx.y * 32 + blockIdx.x;
    const int swz = (linear & 7) * 256 + (linear >> 3);
    const int qb = swz & 31;
    const int bh = swz >> 5;

    const int tid = threadIdx.x;
    const int w = tid >> 6, lane = tid & 63, lc = lane & 15, lq = lane >> 4;
    const int qbase = qb * 64 + w * 16;

    const short* Qp = Qh + (size_t)bh * SEQ * HDD;
    const short* Kp = Kh + (size_t)bh * SEQ * HDD;
    const short* Vp = Vh + (size_t)bh * SEQ * HDD;

    // V transposed: Vt[buf][d*72 + (kv ^ ((d>>3)&7)*8)]  (XOR spreads the
    // formerly-8-way-conflicted write pattern across all banks).
    __shared__ alignas(16) short Vt[2][64 * 72];

    // Q fragment (B-operand layout == A layout): Q[qbase+lc][f*32+lq*8 ..+7]
    bf16x8 aQ[2];
#pragma unroll
    for (int f = 0; f < 2; ++f)
        aQ[f] = *(const bf16x8*)(Qp + (size_t)(qbase + lc) * HDD + f * 32 + lq * 8);

    float mOld = -1e30f, lSum = 0.f;
    floatx4 accO[4];
#pragma unroll
    for (int dt = 0; dt < 4; dt++) accO[dt] = floatx4{0.f, 0.f, 0.f, 0.f};

    // staging map: thread stages kv pair (kv2,kv2+1) x d chunk [d0,d0+8)
    const int kv2 = (tid >> 3) * 2;
    const int d0 = (tid & 7) * 8;
    const int swzb = (tid & 7) << 3;   // == ((d>>3)&7)<<3 for all its 8 d's
    const int kvs_w = kv2 ^ swzb;

    // prologue: stage tile 0 into buf 0
    {
        bf16x8 v0 = *(const bf16x8*)(Vp + (size_t)kv2 * HDD + d0);
        bf16x8 v1 = *(const bf16x8*)(Vp + (size_t)(kv2 + 1) * HDD + d0);
#pragma unroll
        for (int i = 0; i < 8; i++) {
            u32 pk = ((u32)(unsigned short)v0[i]) | (((u32)(unsigned short)v1[i]) << 16);
            *(u32*)(&Vt[0][(d0 + i) * 72 + kvs_w]) = pk;
        }
    }
    __syncthreads();

    const int NT = SEQ / 64;
    for (int kt = 0; kt < NT; ++kt) {
        const int cur = kt & 1;
        const int kv0 = kt * 64;

        // early-issue next tile's V loads (latency hides under QK+softmax+PV)
        bf16x8 nv0{}, nv1{};
        const bool have = (kt + 1 < NT);
        if (have) {
            const short* nvp = Vp + (size_t)(kv0 + 64 + kv2) * HDD + d0;
            nv0 = *(const bf16x8*)nvp;
            nv1 = *(const bf16x8*)(nvp + HDD);
        }

        // QK^T swapped: scores already in log2-units (scale folded into Q)
        floatx4 sc[4];
        __builtin_amdgcn_s_setprio(1);
#pragma unroll
        for (int nt = 0; nt < 4; nt++) {
            floatx4 sv = floatx4{0.f, 0.f, 0.f, 0.f};
#pragma unroll
            for (int f = 0; f < 2; f++) {
                bf16x8 bK = *(const bf16x8*)(Kp + (size_t)(kv0 + nt * 16 + lc) * HDD + f * 32 + lq * 8);
                sv = __builtin_amdgcn_mfma_f32_16x16x32_bf16(bK, aQ[f], sv, 0, 0, 0);
            }
            sc[nt] = sv;
        }
        __builtin_amdgcn_s_setprio(0);

        // online softmax (base 2). Row = q = lc; kv: 16 in-lane + lq over 2 shfls.
        float mx = sc[0][0];
#pragma unroll
        for (int nt = 0; nt < 4; nt++)
#pragma unroll
            for (int r = 0; r < 4; r++) mx = fmaxf(mx, sc[nt][r]);
        mx = fmaxf(mx, __shfl_xor(mx, 16, 64));
        mx = fmaxf(mx, __shfl_xor(mx, 32, 64));
        const float mNew = fmaxf(mOld, mx);
        const float alpha = __builtin_amdgcn_exp2f(mOld - mNew);
        float rsum = 0.f;
#pragma unroll
        for (int nt = 0; nt < 4; nt++)
#pragma unroll
            for (int r = 0; r < 4; r++) {
                float p = __builtin_amdgcn_exp2f(sc[nt][r] - mNew);
                sc[nt][r] = p;
                rsum += p;
            }
        rsum += __shfl_xor(rsum, 16, 64);
        rsum += __shfl_xor(rsum, 32, 64);
        lSum = lSum * alpha + rsum;
        mOld = mNew;

#pragma unroll
        for (int dt = 0; dt < 4; dt++)
#pragma unroll
            for (int r = 0; r < 4; r++) accO[dt][r] *= alpha;

        // pack this lane's P values (P^T[kv=nt*16+lq*4+r][q=lc]) as bf16 pairs
        u32 pw[4][2];
#pragma unroll
        for (int nt = 0; nt < 4; nt++) {
            pw[nt][0] = ((u32)(unsigned short)f2bf(sc[nt][0])) |
                        (((u32)(unsigned short)f2bf(sc[nt][1])) << 16);
            pw[nt][1] = ((u32)(unsigned short)f2bf(sc[nt][2])) |
                        (((u32)(unsigned short)f2bf(sc[nt][3])) << 16);
        }
        // PV operand needs elem j = P^T[f*32+lq*8+j][q=lc]:
        //   src lane = ((lq&1)*2 + (j>>2))*16 + lc, tile nt = 2f + (lq>>1)
        const int srcA = ((lq & 1) << 5) + lc;
        const int srcB = srcA + 16;
        const bool selHi = (lq >> 1) != 0;

        // PV: O^T += V^T * P^T  (A = V^T fragment, B = P^T fragment)
#pragma unroll
        for (int f = 0; f < 2; f++) {
            u32 a0 = (u32)__shfl((int)pw[2 * f][0], srcA, 64);
            u32 a1 = (u32)__shfl((int)pw[2 * f][1], srcA, 64);
            u32 a2 = (u32)__shfl((int)pw[2 * f][0], srcB, 64);
            u32 a3 = (u32)__shfl((int)pw[2 * f][1], srcB, 64);
            u32 b0 = (u32)__shfl((int)pw[2 * f + 1][0], srcA, 64);
            u32 b1 = (u32)__shfl((int)pw[2 * f + 1][1], srcA, 64);
            u32 b2 = (u32)__shfl((int)pw[2 * f + 1][0], srcB, 64);
            u32 b3 = (u32)__shfl((int)pw[2 * f + 1][1], srcB, 64);
            union { u32 u[4]; bf16x8 v; } P;
            P.u[0] = selHi ? b0 : a0;
            P.u[1] = selHi ? b1 : a1;
            P.u[2] = selHi ? b2 : a2;
            P.u[3] = selHi ? b3 : a3;
            __builtin_amdgcn_s_setprio(1);
#pragma unroll
            for (int dt = 0; dt < 4; dt++) {
                const int d = dt * 16 + lc;
                const int kvs = (f * 32 + lq * 8) ^ (((d >> 3) & 7) << 3);
                bf16x8 bV = *(const bf16x8*)(&Vt[cur][d * 72 + kvs]);
                accO[dt] = __builtin_amdgcn_mfma_f32_16x16x32_bf16(bV, P.v, accO[dt], 0, 0, 0);
            }
            __builtin_amdgcn_s_setprio(0);
        }

        // write next tile's V: its previous readers (iter kt-1 PV) are one
        // barrier behind, its next readers (iter kt+1 PV) one barrier ahead.
        if (have) {
            short* dstb = &Vt[cur ^ 1][0];
#pragma unroll
            for (int i = 0; i < 8; i++) {
                u32 pk = ((u32)(unsigned short)nv0[i]) | (((u32)(unsigned short)nv1[i]) << 16);
                *(u32*)(dstb + (d0 + i) * 72 + kvs_w) = pk;
            }
        }
        __syncthreads();
    }

    // epilogue: ctx[b,h,q,d] = O^T[d][q] / l ; lane holds d = dt*16+lq*4+r
    const float inv = 1.0f / lSum;
    float* orow = ctxout + ((size_t)bh * SEQ + qbase + lc) * HDD;
#pragma unroll
    for (int dt = 0; dt < 4; dt++) {
        float4 st;
        st.x = accO[dt][0] * inv;
        st.y = accO[dt][1] * inv;
        st.z = accO[dt][2] * inv;
        st.w = accO[dt][3] * inv;
        *(float4*)(orow + dt * 16 + lq * 4) = st;
    }
}

// ---------------------------------------------------------------------------
// Output projection: out = merged(ctx) @ Wo^T + bo. A gathered from the fp32
// ctx in d_out (head-split layout), out written fp32.
// ---------------------------------------------------------------------------
__global__ __launch_bounds__(256) void outproj_kernel(
    const float* __restrict__ ctxb, const float* __restrict__ wo,
    const float* __restrict__ bo, float* __restrict__ out)
{
    const int m0 = blockIdx.x * 128;
    const int n0 = blockIdx.y * 128;
    const int tid = threadIdx.x;
    const int w = tid >> 6, lane = tid & 63, lc = lane & 15, lq = lane >> 4;
    const int wm = w >> 1, wn = w & 1;

    __shared__ alignas(16) short As[128 * 40];
    __shared__ alignas(16) short Bs[128 * 40];

    floatx4 acc[4][4];
#pragma unroll
    for (int i = 0; i < 4; i++)
#pragma unroll
        for (int j = 0; j < 4; j++) acc[i][j] = floatx4{0.f, 0.f, 0.f, 0.f};

    for (int kt = 0; kt < DM / 32; ++kt) {
        __syncthreads();
#pragma unroll
        for (int c = 0; c < 2; ++c) {
            int chunk = c * 256 + tid;
            int row = chunk >> 2;
            int col = (chunk & 3) * 8;
            int m = m0 + row;
            int b = m >> 11, s = m & 2047;
            int kcol = kt * 32 + col;
            int h = kcol >> 6, hd = kcol & 63;
            stage8f(As + row * 40 + col,
                    ctxb + (((size_t)(b * NH + h)) * SEQ + s) * HDD + hd);
            stage8f(Bs + row * 40 + col, wo + (size_t)(n0 + row) * DM + kt * 32 + col);
        }
        __syncthreads();

        bf16x8 aF[4], bF[4];
#pragma unroll
        for (int i = 0; i < 4; i++)
            aF[i] = *(const bf16x8*)(As + (wm * 64 + i * 16 + lc) * 40 + lq * 8);
#pragma unroll
        for (int j = 0; j < 4; j++)
            bF[j] = *(const bf16x8*)(Bs + (wn * 64 + j * 16 + lc) * 40 + lq * 8);
        __builtin_amdgcn_s_setprio(1);
#pragma unroll
        for (int i = 0; i < 4; i++)
#pragma unroll
            for (int j = 0; j < 4; j++)
                acc[i][j] = __builtin_amdgcn_mfma_f32_16x16x32_bf16(aF[i], bF[j], acc[i][j], 0, 0, 0);
        __builtin_amdgcn_s_setprio(0);
    }

#pragma unroll
    for (int j = 0; j < 4; j++) {
        int n = n0 + wn * 64 + j * 16 + lc;
        float bias = bo[n];
#pragma unroll
        for (int i = 0; i < 4; i++) {
#pragma unroll
            for (int r = 0; r < 4; r++) {
                int m = m0 + wm * 64 + i * 16 + lq * 4 + r;
                out[(size_t)m * DM + n] = acc[i][j][r] + bias;
            }
        }
    }
}

extern "C" void kernel_launch(void* const* d_in, const int* in_sizes, int n_in,
                              void* d_out, int out_size, void* d_ws, size_t ws_size,
                              hipStream_t stream) {
    const float* q  = (const float*)d_in[0];
    const float* k  = (const float*)d_in[1];
    const float* v  = (const float*)d_in[2];
    const float* wq = (const float*)d_in[3];
    const float* bq = (const float*)d_in[4];
    const float* wk = (const float*)d_in[5];
    const float* bk = (const float*)d_in[6];
    const float* wv = (const float*)d_in[7];
    const float* bv = (const float*)d_in[8];
    const float* wo = (const float*)d_in[9];
    const float* bo = (const float*)d_in[10];

    float* out0 = (float*)d_out;                          // [B,S,D] fp32
    float* ctx  = out0 + (size_t)BB * SEQ * DM;           // [B,H,S,HD] fp32

    short* Qh = (short*)d_ws;
    short* Kh = Qh + (size_t)BB * NH * SEQ * HDD;
    short* Vh = Kh + (size_t)BB * NH * SEQ * HDD;

    proj_kernel<<<dim3(64, 8, 3), 256, 0, stream>>>(q, k, v, wq, bq, wk, bk, wv, bv, Qh, Kh, Vh);
    attn_kernel<<<dim3(32, 64), 256, 0, stream>>>(Qh, Kh, Vh, ctx);
    outproj_kernel<<<dim3(64, 8), 256, 0, stream>>>(ctx, wo, bo, out0);
}

// Round 3
// 560.994 us; speedup vs baseline: 1.0369x; 1.0369x over previous
//
#include <hip/hip_runtime.h>
#include <hip/hip_bf16.h>

#define HDD 64
#define NH 16
#define SEQ 2048
#define DM 1024
#define BB 4

using bf16x8 = __attribute__((ext_vector_type(8))) short;
using bf16x4 = __attribute__((ext_vector_type(4))) short;
using floatx4 = __attribute__((ext_vector_type(4))) float;
typedef unsigned int u32;

__device__ __forceinline__ short f2bf(float f) {
    __hip_bfloat16 h = __float2bfloat16(f);
    union { __hip_bfloat16 h; short s; } c;
    c.h = h;
    return c.s;
}

// Stage 8 contiguous fp32 elements from global into LDS as bf16.
__device__ __forceinline__ void stage8f(short* dst, const float* s) {
    float4 a = *(const float4*)s;
    float4 b = *(const float4*)(s + 4);
    bf16x8 r;
    r[0] = f2bf(a.x); r[1] = f2bf(a.y); r[2] = f2bf(a.z); r[3] = f2bf(a.w);
    r[4] = f2bf(b.x); r[5] = f2bf(b.y); r[6] = f2bf(b.z); r[7] = f2bf(b.w);
    *(bf16x8*)dst = r;
}

// ---------------------------------------------------------------------------
// Weight convert: fp32 [1024][1024] -> bf16 same layout, for wq/wk/wv/wo.
// ---------------------------------------------------------------------------
__global__ __launch_bounds__(256) void wconv_kernel(
    const float* __restrict__ w0, const float* __restrict__ w1,
    const float* __restrict__ w2, const float* __restrict__ w3,
    short* __restrict__ o0, short* __restrict__ o1,
    short* __restrict__ o2, short* __restrict__ o3)
{
    const int z = blockIdx.y;
    const float* src = (z == 0) ? w0 : (z == 1) ? w1 : (z == 2) ? w2 : w3;
    short* dst       = (z == 0) ? o0 : (z == 1) ? o1 : (z == 2) ? o2 : o3;
    size_t i = ((size_t)blockIdx.x * 256 + threadIdx.x) * 8;
    stage8f(dst + i, src + i);
}

// ---------------------------------------------------------------------------
// QKV projection: Y = X @ W^T + b (fp32 X, bf16 W), written head-split
// as [B,H,S,HD] bf16. For Q (z==0), 0.125*log2(e) is folded in so the
// attention kernel can use exp2 on unscaled MFMA scores.
// ---------------------------------------------------------------------------
__global__ __launch_bounds__(256) void proj_kernel(
    const float* __restrict__ q, const float* __restrict__ k, const float* __restrict__ v,
    const short* __restrict__ wqb, const float* __restrict__ bq,
    const short* __restrict__ wkb, const float* __restrict__ bk,
    const short* __restrict__ wvb, const float* __restrict__ bv,
    short* __restrict__ Qh, short* __restrict__ Kh, short* __restrict__ Vh)
{
    const int z = blockIdx.z;
    const float* X  = (z == 0) ? q   : (z == 1) ? k   : v;
    const short* Wb = (z == 0) ? wqb : (z == 1) ? wkb : wvb;
    const float* Bp = (z == 0) ? bq  : (z == 1) ? bk  : bv;
    short* Dst      = (z == 0) ? Qh  : (z == 1) ? Kh  : Vh;
    const float qscale = (z == 0) ? (0.125f * 1.44269504088896f) : 1.0f;

    const int m0 = blockIdx.x * 128;
    const int n0 = blockIdx.y * 128;
    const int tid = threadIdx.x;
    const int w = tid >> 6, lane = tid & 63, lc = lane & 15, lq = lane >> 4;
    const int wm = w >> 1, wn = w & 1;

    __shared__ alignas(16) short As[128 * 40];
    __shared__ alignas(16) short Bs[128 * 40];

    floatx4 acc[4][4];
#pragma unroll
    for (int i = 0; i < 4; i++)
#pragma unroll
        for (int j = 0; j < 4; j++) acc[i][j] = floatx4{0.f, 0.f, 0.f, 0.f};

    for (int kt = 0; kt < DM / 32; ++kt) {
        __syncthreads();
#pragma unroll
        for (int c = 0; c < 2; ++c) {
            int chunk = c * 256 + tid;
            int row = chunk >> 2;
            int col = (chunk & 3) * 8;
            stage8f(As + row * 40 + col, X + (size_t)(m0 + row) * DM + kt * 32 + col);
            *(bf16x8*)(Bs + row * 40 + col) =
                *(const bf16x8*)(Wb + (size_t)(n0 + row) * DM + kt * 32 + col);
        }
        __syncthreads();

        bf16x8 aF[4], bF[4];
#pragma unroll
        for (int i = 0; i < 4; i++)
            aF[i] = *(const bf16x8*)(As + (wm * 64 + i * 16 + lc) * 40 + lq * 8);
#pragma unroll
        for (int j = 0; j < 4; j++)
            bF[j] = *(const bf16x8*)(Bs + (wn * 64 + j * 16 + lc) * 40 + lq * 8);
        __builtin_amdgcn_s_setprio(1);
#pragma unroll
        for (int i = 0; i < 4; i++)
#pragma unroll
            for (int j = 0; j < 4; j++)
                acc[i][j] = __builtin_amdgcn_mfma_f32_16x16x32_bf16(aF[i], bF[j], acc[i][j], 0, 0, 0);
        __builtin_amdgcn_s_setprio(0);
    }

#pragma unroll
    for (int j = 0; j < 4; j++) {
        int n = n0 + wn * 64 + j * 16 + lc;
        float bias = Bp[n];
        int h = n >> 6, hd = n & 63;
#pragma unroll
        for (int i = 0; i < 4; i++) {
#pragma unroll
            for (int r = 0; r < 4; r++) {
                int m = m0 + wm * 64 + i * 16 + lq * 4 + r;
                int b = m >> 11, s = m & 2047;
                float val = (acc[i][j][r] + bias) * qscale;
                Dst[(((size_t)(b * NH + h)) * SEQ + s) * HDD + hd] = f2bf(val);
            }
        }
    }
}

// ---------------------------------------------------------------------------
// Flash attention, swapped-operand QK^T, 8 waves/block (128 q-rows):
//   S^T = mfma(A=K, B=Q)  ->  lane (lc,lq) holds S^T[kv=nt*16+lq*4+r][q=lc]
// Softmax: in-lane + 2 shfl_xor; defer-max (T13, THR=8 in log2 units).
// P in registers -> PV operands via shuffles. V^T in XOR-swizzled,
// double-buffered LDS shared by all 8 waves, one barrier per tile.
// ---------------------------------------------------------------------------
__global__ __launch_bounds__(512) void attn_kernel(
    const short* __restrict__ Qh, const short* __restrict__ Kh,
    const short* __restrict__ Vh, float* __restrict__ ctxout,
    short* __restrict__ ctxb)
{
    // XCD swizzle: 1024 blocks / 8 XCDs -> each XCD owns 8 (b,h) pairs
    // (K+V = 8 * 512KB = 4MB = one XCD L2).
    const int linear = blockIdx.y * 16 + blockIdx.x;
    const int swz = (linear & 7) * 128 + (linear >> 3);
    const int qb = swz & 15;
    const int bh = swz >> 4;

    const int tid = threadIdx.x;
    const int w = tid >> 6, lane = tid & 63, lc = lane & 15, lq = lane >> 4;
    const int qbase = qb * 128 + w * 16;

    const short* Qp = Qh + (size_t)bh * SEQ * HDD;
    const short* Kp = Kh + (size_t)bh * SEQ * HDD;
    const short* Vp = Vh + (size_t)bh * SEQ * HDD;

    // V transposed: Vt[buf][d*72 + (kv ^ ((d>>3)&7)*8)]
    __shared__ alignas(16) short Vt[2][64 * 72];

    bf16x8 aQ[2];
#pragma unroll
    for (int f = 0; f < 2; ++f)
        aQ[f] = *(const bf16x8*)(Qp + (size_t)(qbase + lc) * HDD + f * 32 + lq * 8);

    float mOld = -1e30f, lSum = 0.f;
    floatx4 accO[4];
#pragma unroll
    for (int dt = 0; dt < 4; dt++) accO[dt] = floatx4{0.f, 0.f, 0.f, 0.f};

    // staging map (512 threads): thread stages kv pair (kv2,kv2+1) x 4 d's
    const int kv2 = (tid >> 4) * 2;          // 0..62
    const int d0 = (tid & 15) * 4;           // 0..60, chunk of 4 within one 8-block
    const int swzb = ((d0 >> 3) & 7) << 3;   // same for all 4 d's of this thread
    const int kvs_w = kv2 ^ swzb;

    // prologue: stage tile 0 into buf 0
    {
        const short* vp = Vp + (size_t)kv2 * HDD + d0;
        bf16x4 v0 = *(const bf16x4*)vp;
        bf16x4 v1 = *(const bf16x4*)(vp + HDD);
#pragma unroll
        for (int i = 0; i < 4; i++) {
            u32 pk = ((u32)(unsigned short)v0[i]) | (((u32)(unsigned short)v1[i]) << 16);
            *(u32*)(&Vt[0][(d0 + i) * 72 + kvs_w]) = pk;
        }
    }
    __syncthreads();

    const int NT = SEQ / 64;
    for (int kt = 0; kt < NT; ++kt) {
        const int cur = kt & 1;
        const int kv0 = kt * 64;

        // early-issue next tile's V loads (hide under QK+softmax+PV)
        bf16x4 nv0{}, nv1{};
        const bool have = (kt + 1 < NT);
        if (have) {
            const short* nvp = Vp + (size_t)(kv0 + 64 + kv2) * HDD + d0;
            nv0 = *(const bf16x4*)nvp;
            nv1 = *(const bf16x4*)(nvp + HDD);
        }

        // QK^T swapped: scores already in log2-units (scale folded into Q)
        floatx4 sc[4];
        __builtin_amdgcn_s_setprio(1);
#pragma unroll
        for (int nt = 0; nt < 4; nt++) {
            floatx4 sv = floatx4{0.f, 0.f, 0.f, 0.f};
#pragma unroll
            for (int f = 0; f < 2; f++) {
                bf16x8 bK = *(const bf16x8*)(Kp + (size_t)(kv0 + nt * 16 + lc) * HDD + f * 32 + lq * 8);
                sv = __builtin_amdgcn_mfma_f32_16x16x32_bf16(bK, aQ[f], sv, 0, 0, 0);
            }
            sc[nt] = sv;
        }
        __builtin_amdgcn_s_setprio(0);

        // online softmax (base 2), defer-max with THR=8
        float mx = sc[0][0];
#pragma unroll
        for (int nt = 0; nt < 4; nt++)
#pragma unroll
            for (int r = 0; r < 4; r++) mx = fmaxf(mx, sc[nt][r]);
        mx = fmaxf(mx, __shfl_xor(mx, 16, 64));
        mx = fmaxf(mx, __shfl_xor(mx, 32, 64));
        if (!__all(mx - mOld <= 8.0f)) {
            const float mNew = fmaxf(mOld, mx);
            const float alpha = __builtin_amdgcn_exp2f(mOld - mNew);
            lSum *= alpha;
#pragma unroll
            for (int dt = 0; dt < 4; dt++)
#pragma unroll
                for (int r = 0; r < 4; r++) accO[dt][r] *= alpha;
            mOld = mNew;
        }
        float rsum = 0.f;
#pragma unroll
        for (int nt = 0; nt < 4; nt++)
#pragma unroll
            for (int r = 0; r < 4; r++) {
                float p = __builtin_amdgcn_exp2f(sc[nt][r] - mOld);
                sc[nt][r] = p;
                rsum += p;
            }
        rsum += __shfl_xor(rsum, 16, 64);
        rsum += __shfl_xor(rsum, 32, 64);
        lSum += rsum;

        // pack P (P^T[kv=nt*16+lq*4+r][q=lc]) as bf16 pairs
        u32 pw[4][2];
#pragma unroll
        for (int nt = 0; nt < 4; nt++) {
            pw[nt][0] = ((u32)(unsigned short)f2bf(sc[nt][0])) |
                        (((u32)(unsigned short)f2bf(sc[nt][1])) << 16);
            pw[nt][1] = ((u32)(unsigned short)f2bf(sc[nt][2])) |
                        (((u32)(unsigned short)f2bf(sc[nt][3])) << 16);
        }
        // PV operand elem j = P^T[f*32+lq*8+j][q=lc]:
        //   src lane = ((lq&1)*2 + (j>>2))*16 + lc, tile nt = 2f + (lq>>1)
        const int srcA = ((lq & 1) << 5) + lc;
        const int srcB = srcA + 16;
        const bool selHi = (lq >> 1) != 0;

#pragma unroll
        for (int f = 0; f < 2; f++) {
            u32 a0 = (u32)__shfl((int)pw[2 * f][0], srcA, 64);
            u32 a1 = (u32)__shfl((int)pw[2 * f][1], srcA, 64);
            u32 a2 = (u32)__shfl((int)pw[2 * f][0], srcB, 64);
            u32 a3 = (u32)__shfl((int)pw[2 * f][1], srcB, 64);
            u32 b0 = (u32)__shfl((int)pw[2 * f + 1][0], srcA, 64);
            u32 b1 = (u32)__shfl((int)pw[2 * f + 1][1], srcA, 64);
            u32 b2 = (u32)__shfl((int)pw[2 * f + 1][0], srcB, 64);
            u32 b3 = (u32)__shfl((int)pw[2 * f + 1][1], srcB, 64);
            union { u32 u[4]; bf16x8 v; } P;
            P.u[0] = selHi ? b0 : a0;
            P.u[1] = selHi ? b1 : a1;
            P.u[2] = selHi ? b2 : a2;
            P.u[3] = selHi ? b3 : a3;
            __builtin_amdgcn_s_setprio(1);
#pragma unroll
            for (int dt = 0; dt < 4; dt++) {
                const int d = dt * 16 + lc;
                const int kvs = (f * 32 + lq * 8) ^ (((d >> 3) & 7) << 3);
                bf16x8 bV = *(const bf16x8*)(&Vt[cur][d * 72 + kvs]);
                accO[dt] = __builtin_amdgcn_mfma_f32_16x16x32_bf16(bV, P.v, accO[dt], 0, 0, 0);
            }
            __builtin_amdgcn_s_setprio(0);
        }

        // write next tile's V into the other buffer
        if (have) {
            short* dstb = &Vt[cur ^ 1][0];
#pragma unroll
            for (int i = 0; i < 4; i++) {
                u32 pk = ((u32)(unsigned short)nv0[i]) | (((u32)(unsigned short)nv1[i]) << 16);
                *(u32*)(dstb + (d0 + i) * 72 + kvs_w) = pk;
            }
        }
        __syncthreads();
    }

    // epilogue: ctx[b,h,q,d] = O^T[d][q] / l (fp32 to d_out, bf16 to ws)
    const float inv = 1.0f / lSum;
    const size_t rowoff = ((size_t)bh * SEQ + qbase + lc) * HDD;
    float* orow = ctxout + rowoff;
    short* brow = ctxb + rowoff;
#pragma unroll
    for (int dt = 0; dt < 4; dt++) {
        float4 st;
        st.x = accO[dt][0] * inv;
        st.y = accO[dt][1] * inv;
        st.z = accO[dt][2] * inv;
        st.w = accO[dt][3] * inv;
        *(float4*)(orow + dt * 16 + lq * 4) = st;
        uint2 bb;
        bb.x = ((u32)(unsigned short)f2bf(st.x)) | (((u32)(unsigned short)f2bf(st.y)) << 16);
        bb.y = ((u32)(unsigned short)f2bf(st.z)) | (((u32)(unsigned short)f2bf(st.w)) << 16);
        *(uint2*)(brow + dt * 16 + lq * 4) = bb;
    }
}

// ---------------------------------------------------------------------------
// Output projection: out = merged(ctx) @ Wo^T + bo. Both operands bf16
// (ctxb gathered head-split, wob), out written fp32.
// ---------------------------------------------------------------------------
__global__ __launch_bounds__(256) void outproj_kernel(
    const short* __restrict__ ctxb, const short* __restrict__ wob,
    const float* __restrict__ bo, float* __restrict__ out)
{
    const int m0 = blockIdx.x * 128;
    const int n0 = blockIdx.y * 128;
    const int tid = threadIdx.x;
    const int w = tid >> 6, lane = tid & 63, lc = lane & 15, lq = lane >> 4;
    const int wm = w >> 1, wn = w & 1;

    __shared__ alignas(16) short As[128 * 40];
    __shared__ alignas(16) short Bs[128 * 40];

    floatx4 acc[4][4];
#pragma unroll
    for (int i = 0; i < 4; i++)
#pragma unroll
        for (int j = 0; j < 4; j++) acc[i][j] = floatx4{0.f, 0.f, 0.f, 0.f};

    for (int kt = 0; kt < DM / 32; ++kt) {
        __syncthreads();
#pragma unroll
        for (int c = 0; c < 2; ++c) {
            int chunk = c * 256 + tid;
            int row = chunk >> 2;
            int col = (chunk & 3) * 8;
            int m = m0 + row;
            int b = m >> 11, s = m & 2047;
            int kcol = kt * 32 + col;
            int h = kcol >> 6, hd = kcol & 63;
            *(bf16x8*)(As + row * 40 + col) =
                *(const bf16x8*)(ctxb + (((size_t)(b * NH + h)) * SEQ + s) * HDD + hd);
            *(bf16x8*)(Bs + row * 40 + col) =
                *(const bf16x8*)(wob + (size_t)(n0 + row) * DM + kt * 32 + col);
        }
        __syncthreads();

        bf16x8 aF[4], bF[4];
#pragma unroll
        for (int i = 0; i < 4; i++)
            aF[i] = *(const bf16x8*)(As + (wm * 64 + i * 16 + lc) * 40 + lq * 8);
#pragma unroll
        for (int j = 0; j < 4; j++)
            bF[j] = *(const bf16x8*)(Bs + (wn * 64 + j * 16 + lc) * 40 + lq * 8);
        __builtin_amdgcn_s_setprio(1);
#pragma unroll
        for (int i = 0; i < 4; i++)
#pragma unroll
            for (int j = 0; j < 4; j++)
                acc[i][j] = __builtin_amdgcn_mfma_f32_16x16x32_bf16(aF[i], bF[j], acc[i][j], 0, 0, 0);
        __builtin_amdgcn_s_setprio(0);
    }

#pragma unroll
    for (int j = 0; j < 4; j++) {
        int n = n0 + wn * 64 + j * 16 + lc;
        float bias = bo[n];
#pragma unroll
        for (int i = 0; i < 4; i++) {
#pragma unroll
            for (int r = 0; r < 4; r++) {
                int m = m0 + wm * 64 + i * 16 + lq * 4 + r;
                out[(size_t)m * DM + n] = acc[i][j][r] + bias;
            }
        }
    }
}

extern "C" void kernel_launch(void* const* d_in, const int* in_sizes, int n_in,
                              void* d_out, int out_size, void* d_ws, size_t ws_size,
                              hipStream_t stream) {
    const float* q  = (const float*)d_in[0];
    const float* k  = (const float*)d_in[1];
    const float* v  = (const float*)d_in[2];
    const float* wq = (const float*)d_in[3];
    const float* bq = (const float*)d_in[4];
    const float* wk = (const float*)d_in[5];
    const float* bk = (const float*)d_in[6];
    const float* wv = (const float*)d_in[7];
    const float* bv = (const float*)d_in[8];
    const float* wo = (const float*)d_in[9];
    const float* bo = (const float*)d_in[10];

    float* out0 = (float*)d_out;                          // [B,S,D] fp32
    float* ctx  = out0 + (size_t)BB * SEQ * DM;           // [B,H,S,HD] fp32

    const size_t NELEM = (size_t)BB * NH * SEQ * HDD;     // 8.39M
    short* Qh   = (short*)d_ws;
    short* Kh   = Qh + NELEM;
    short* Vh   = Kh + NELEM;
    short* ctxb = Vh + NELEM;
    short* Wqb  = ctxb + NELEM;
    short* Wkb  = Wqb + (size_t)DM * DM;
    short* Wvb  = Wkb + (size_t)DM * DM;
    short* Wob  = Wvb + (size_t)DM * DM;
    // total ws: 4*16.78MB + 4*2MB = 75.1MB

    wconv_kernel<<<dim3(512, 4), 256, 0, stream>>>(wq, wk, wv, wo, Wqb, Wkb, Wvb, Wob);
    proj_kernel<<<dim3(64, 8, 3), 256, 0, stream>>>(q, k, v, Wqb, bq, Wkb, bk, Wvb, bv, Qh, Kh, Vh);
    attn_kernel<<<dim3(16, 64), 512, 0, stream>>>(Qh, Kh, Vh, ctx, ctxb);
    outproj_kernel<<<dim3(64, 8), 256, 0, stream>>>(ctxb, Wob, bo, out0);
}

// Round 4
// 516.005 us; speedup vs baseline: 1.1273x; 1.0872x over previous
//
#include <hip/hip_runtime.h>
#include <hip/hip_bf16.h>

#define HDD 64
#define NH 16
#define SEQ 2048
#define DM 1024
#define BB 4

using bf16x8 = __attribute__((ext_vector_type(8))) short;
using bf16x4 = __attribute__((ext_vector_type(4))) short;
using floatx4 = __attribute__((ext_vector_type(4))) float;
typedef unsigned int u32;

__device__ __forceinline__ short f2bf(float f) {
    __hip_bfloat16 h = __float2bfloat16(f);
    union { __hip_bfloat16 h; short s; } c;
    c.h = h;
    return c.s;
}

// Convert 8 contiguous fp32 -> 8 bf16.
__device__ __forceinline__ void stage8f(short* dst, const float* s) {
    float4 a = *(const float4*)s;
    float4 b = *(const float4*)(s + 4);
    bf16x8 r;
    r[0] = f2bf(a.x); r[1] = f2bf(a.y); r[2] = f2bf(a.z); r[3] = f2bf(a.w);
    r[4] = f2bf(b.x); r[5] = f2bf(b.y); r[6] = f2bf(b.z); r[7] = f2bf(b.w);
    *(bf16x8*)dst = r;
}

__device__ __forceinline__ float vmax4(floatx4 v) {
    return fmaxf(fmaxf(v[0], v[1]), fmaxf(v[2], v[3]));
}

// ---------------------------------------------------------------------------
// Bulk fp32->bf16 convert: 4 weight matrices (1M elems) + 3 inputs (8.39M).
// ---------------------------------------------------------------------------
__global__ __launch_bounds__(256) void conv_kernel(
    const float* __restrict__ w0, const float* __restrict__ w1,
    const float* __restrict__ w2, const float* __restrict__ w3,
    const float* __restrict__ x0, const float* __restrict__ x1,
    const float* __restrict__ x2,
    short* __restrict__ ow0, short* __restrict__ ow1,
    short* __restrict__ ow2, short* __restrict__ ow3,
    short* __restrict__ ox0, short* __restrict__ ox1,
    short* __restrict__ ox2)
{
    const int z = blockIdx.y;
    const float* src;
    short* dst;
    switch (z) {
        case 0: src = w0; dst = ow0; break;
        case 1: src = w1; dst = ow1; break;
        case 2: src = w2; dst = ow2; break;
        case 3: src = w3; dst = ow3; break;
        case 4: src = x0; dst = ox0; break;
        case 5: src = x1; dst = ox1; break;
        default: src = x2; dst = ox2; break;
    }
    if (z < 4 && blockIdx.x >= 512) return;   // weights: 1M elems only
    size_t i = ((size_t)blockIdx.x * 256 + threadIdx.x) * 8;
    stage8f(dst + i, src + i);
}

// ---------------------------------------------------------------------------
// QKV projection: Y = X @ W^T + b (both operands bf16), written head-split
// as [B,H,S,HD] bf16. For Q (z==0), 0.125*log2(e) is folded in so the
// attention kernel can use exp2 on unscaled MFMA scores.
// ---------------------------------------------------------------------------
__global__ __launch_bounds__(256) void proj_kernel(
    const short* __restrict__ xq, const short* __restrict__ xk, const short* __restrict__ xv,
    const short* __restrict__ wqb, const float* __restrict__ bq,
    const short* __restrict__ wkb, const float* __restrict__ bk,
    const short* __restrict__ wvb, const float* __restrict__ bv,
    short* __restrict__ Qh, short* __restrict__ Kh, short* __restrict__ Vh)
{
    const int z = blockIdx.z;
    const short* X  = (z == 0) ? xq  : (z == 1) ? xk  : xv;
    const short* Wb = (z == 0) ? wqb : (z == 1) ? wkb : wvb;
    const float* Bp = (z == 0) ? bq  : (z == 1) ? bk  : bv;
    short* Dst      = (z == 0) ? Qh  : (z == 1) ? Kh  : Vh;
    const float qscale = (z == 0) ? (0.125f * 1.44269504088896f) : 1.0f;

    const int m0 = blockIdx.x * 128;
    const int n0 = blockIdx.y * 128;
    const int tid = threadIdx.x;
    const int w = tid >> 6, lane = tid & 63, lc = lane & 15, lq = lane >> 4;
    const int wm = w >> 1, wn = w & 1;

    __shared__ alignas(16) short As[128 * 40];
    __shared__ alignas(16) short Bs[128 * 40];

    floatx4 acc[4][4];
#pragma unroll
    for (int i = 0; i < 4; i++)
#pragma unroll
        for (int j = 0; j < 4; j++) acc[i][j] = floatx4{0.f, 0.f, 0.f, 0.f};

    for (int kt = 0; kt < DM / 32; ++kt) {
        __syncthreads();
#pragma unroll
        for (int c = 0; c < 2; ++c) {
            int chunk = c * 256 + tid;
            int row = chunk >> 2;
            int col = (chunk & 3) * 8;
            *(bf16x8*)(As + row * 40 + col) =
                *(const bf16x8*)(X + (size_t)(m0 + row) * DM + kt * 32 + col);
            *(bf16x8*)(Bs + row * 40 + col) =
                *(const bf16x8*)(Wb + (size_t)(n0 + row) * DM + kt * 32 + col);
        }
        __syncthreads();

        bf16x8 aF[4], bF[4];
#pragma unroll
        for (int i = 0; i < 4; i++)
            aF[i] = *(const bf16x8*)(As + (wm * 64 + i * 16 + lc) * 40 + lq * 8);
#pragma unroll
        for (int j = 0; j < 4; j++)
            bF[j] = *(const bf16x8*)(Bs + (wn * 64 + j * 16 + lc) * 40 + lq * 8);
        __builtin_amdgcn_s_setprio(1);
#pragma unroll
        for (int i = 0; i < 4; i++)
#pragma unroll
            for (int j = 0; j < 4; j++)
                acc[i][j] = __builtin_amdgcn_mfma_f32_16x16x32_bf16(aF[i], bF[j], acc[i][j], 0, 0, 0);
        __builtin_amdgcn_s_setprio(0);
    }

#pragma unroll
    for (int j = 0; j < 4; j++) {
        int n = n0 + wn * 64 + j * 16 + lc;
        float bias = Bp[n];
        int h = n >> 6, hd = n & 63;
#pragma unroll
        for (int i = 0; i < 4; i++) {
#pragma unroll
            for (int r = 0; r < 4; r++) {
                int m = m0 + wm * 64 + i * 16 + lq * 4 + r;
                int b = m >> 11, s = m & 2047;
                float val = (acc[i][j][r] + bias) * qscale;
                Dst[(((size_t)(b * NH + h)) * SEQ + s) * HDD + hd] = f2bf(val);
            }
        }
    }
}

// ---------------------------------------------------------------------------
// Flash attention, swapped-operand QK^T, 8 waves/block (128 q-rows),
// TWO kv-tiles (128 kv) per iteration for ILP + half the barriers:
//   S^T = mfma(A=K, B=Q)  ->  lane (lc,lq) holds S^T[kv=nt*16+lq*4+r][q=lc]
// Softmax: in-lane trees + 2 shfl_xor per 128 kv; defer-max (THR=8, log2).
// P in registers -> PV operands via shuffles. V^T in XOR-swizzled,
// double-buffered LDS (2 tiles/buf), one barrier per 128 kv.
// ---------------------------------------------------------------------------
__global__ __launch_bounds__(512) void attn_kernel(
    const short* __restrict__ Qh, const short* __restrict__ Kh,
    const short* __restrict__ Vh, float* __restrict__ ctxout,
    short* __restrict__ ctxb)
{
    // XCD swizzle: 1024 blocks / 8 XCDs -> each XCD owns 8 (b,h) pairs.
    const int linear = blockIdx.y * 16 + blockIdx.x;
    const int swz = (linear & 7) * 128 + (linear >> 3);
    const int qb = swz & 15;
    const int bh = swz >> 4;

    const int tid = threadIdx.x;
    const int w = tid >> 6, lane = tid & 63, lc = lane & 15, lq = lane >> 4;
    const int qbase = qb * 128 + w * 16;

    const short* Qp = Qh + (size_t)bh * SEQ * HDD;
    const short* Kp = Kh + (size_t)bh * SEQ * HDD;
    const short* Vp = Vh + (size_t)bh * SEQ * HDD;

    // V transposed: Vt[buf][half][d*72 + (kv ^ ((d>>3)&7)*8)]
    __shared__ alignas(16) short Vt[2][2][64 * 72];

    bf16x8 aQ[2];
#pragma unroll
    for (int f = 0; f < 2; ++f)
        aQ[f] = *(const bf16x8*)(Qp + (size_t)(qbase + lc) * HDD + f * 32 + lq * 8);

    float mOld = -1e30f, lSum = 0.f;
    floatx4 accO[4];
#pragma unroll
    for (int dt = 0; dt < 4; dt++) accO[dt] = floatx4{0.f, 0.f, 0.f, 0.f};

    // staging map: 256 threads per half-tile; thread stages 2 kv rows x 8 d
    const int half = tid >> 8;
    const int t8 = tid & 255;
    const int kv2 = (t8 >> 3) * 2;
    const int d0 = (t8 & 7) * 8;
    const int swzb = (t8 & 7) << 3;
    const int kvs_w = kv2 ^ swzb;

    // prologue: stage pair 0 into buf 0
    {
        const short* vp = Vp + (size_t)(half * 64 + kv2) * HDD + d0;
        bf16x8 v0 = *(const bf16x8*)vp;
        bf16x8 v1 = *(const bf16x8*)(vp + HDD);
        short* dstb = &Vt[0][half][0];
#pragma unroll
        for (int i = 0; i < 8; i++) {
            u32 pk = ((u32)(unsigned short)v0[i]) | (((u32)(unsigned short)v1[i]) << 16);
            *(u32*)(dstb + (d0 + i) * 72 + kvs_w) = pk;
        }
    }
    __syncthreads();

    const int srcA = ((lq & 1) << 5) + lc;
    const int srcB = srcA + 16;
    const bool selHi = (lq >> 1) != 0;

    const int NP = SEQ / 128;  // 16 iterations
    for (int kp = 0; kp < NP; ++kp) {
        const int cur = kp & 1;
        const int kv0 = kp * 128;
        const bool have = (kp + 1 < NP);

        // early-issue next pair's V loads (hide under QK+softmax+PV)
        bf16x8 nv0{}, nv1{};
        if (have) {
            const short* nvp = Vp + (size_t)(kv0 + 128 + half * 64 + kv2) * HDD + d0;
            nv0 = *(const bf16x8*)nvp;
            nv1 = *(const bf16x8*)(nvp + HDD);
        }

        // QK^T for both tiles (scores in log2-units; scale folded into Q)
        floatx4 sc0[4], sc1[4];
        __builtin_amdgcn_s_setprio(1);
#pragma unroll
        for (int nt = 0; nt < 4; nt++) {
            floatx4 sv = floatx4{0.f, 0.f, 0.f, 0.f};
#pragma unroll
            for (int f = 0; f < 2; f++) {
                bf16x8 bK = *(const bf16x8*)(Kp + (size_t)(kv0 + nt * 16 + lc) * HDD + f * 32 + lq * 8);
                sv = __builtin_amdgcn_mfma_f32_16x16x32_bf16(bK, aQ[f], sv, 0, 0, 0);
            }
            sc0[nt] = sv;
        }
#pragma unroll
        for (int nt = 0; nt < 4; nt++) {
            floatx4 sv = floatx4{0.f, 0.f, 0.f, 0.f};
#pragma unroll
            for (int f = 0; f < 2; f++) {
                bf16x8 bK = *(const bf16x8*)(Kp + (size_t)(kv0 + 64 + nt * 16 + lc) * HDD + f * 32 + lq * 8);
                sv = __builtin_amdgcn_mfma_f32_16x16x32_bf16(bK, aQ[f], sv, 0, 0, 0);
            }
            sc1[nt] = sv;
        }
        __builtin_amdgcn_s_setprio(0);

        // max over 128 kv: in-lane tree + 2 shfl
        float ma = fmaxf(fmaxf(vmax4(sc0[0]), vmax4(sc0[1])),
                         fmaxf(vmax4(sc0[2]), vmax4(sc0[3])));
        float mb = fmaxf(fmaxf(vmax4(sc1[0]), vmax4(sc1[1])),
                         fmaxf(vmax4(sc1[2]), vmax4(sc1[3])));
        float mx = fmaxf(ma, mb);
        mx = fmaxf(mx, __shfl_xor(mx, 16, 64));
        mx = fmaxf(mx, __shfl_xor(mx, 32, 64));
        if (!__all(mx - mOld <= 8.0f)) {
            const float mNew = fmaxf(mOld, mx);
            const float alpha = __builtin_amdgcn_exp2f(mOld - mNew);
            lSum *= alpha;
#pragma unroll
            for (int dt = 0; dt < 4; dt++)
#pragma unroll
                for (int r = 0; r < 4; r++) accO[dt][r] *= alpha;
            mOld = mNew;
        }

        // exp2 + tree-sum
        float part[8];
#pragma unroll
        for (int nt = 0; nt < 4; nt++) {
            floatx4 p0 = sc0[nt], p1 = sc1[nt];
#pragma unroll
            for (int r = 0; r < 4; r++) {
                p0[r] = __builtin_amdgcn_exp2f(p0[r] - mOld);
                p1[r] = __builtin_amdgcn_exp2f(p1[r] - mOld);
            }
            sc0[nt] = p0; sc1[nt] = p1;
            part[nt]     = (p0[0] + p0[1]) + (p0[2] + p0[3]);
            part[4 + nt] = (p1[0] + p1[1]) + (p1[2] + p1[3]);
        }
        float rsum = ((part[0] + part[1]) + (part[2] + part[3])) +
                     ((part[4] + part[5]) + (part[6] + part[7]));
        rsum += __shfl_xor(rsum, 16, 64);
        rsum += __shfl_xor(rsum, 32, 64);
        lSum += rsum;

        // PV per tile: pack P, redistribute via shuffles, 8 MFMA
#pragma unroll
        for (int t = 0; t < 2; t++) {
            floatx4* sc = (t == 0) ? sc0 : sc1;
            const short* vtb = &Vt[cur][t][0];
            u32 pw[4][2];
#pragma unroll
            for (int nt = 0; nt < 4; nt++) {
                pw[nt][0] = ((u32)(unsigned short)f2bf(sc[nt][0])) |
                            (((u32)(unsigned short)f2bf(sc[nt][1])) << 16);
                pw[nt][1] = ((u32)(unsigned short)f2bf(sc[nt][2])) |
                            (((u32)(unsigned short)f2bf(sc[nt][3])) << 16);
            }
#pragma unroll
            for (int f = 0; f < 2; f++) {
                u32 a0 = (u32)__shfl((int)pw[2 * f][0], srcA, 64);
                u32 a1 = (u32)__shfl((int)pw[2 * f][1], srcA, 64);
                u32 a2 = (u32)__shfl((int)pw[2 * f][0], srcB, 64);
                u32 a3 = (u32)__shfl((int)pw[2 * f][1], srcB, 64);
                u32 b0 = (u32)__shfl((int)pw[2 * f + 1][0], srcA, 64);
                u32 b1 = (u32)__shfl((int)pw[2 * f + 1][1], srcA, 64);
                u32 b2 = (u32)__shfl((int)pw[2 * f + 1][0], srcB, 64);
                u32 b3 = (u32)__shfl((int)pw[2 * f + 1][1], srcB, 64);
                union { u32 u[4]; bf16x8 v; } P;
                P.u[0] = selHi ? b0 : a0;
                P.u[1] = selHi ? b1 : a1;
                P.u[2] = selHi ? b2 : a2;
                P.u[3] = selHi ? b3 : a3;
                __builtin_amdgcn_s_setprio(1);
#pragma unroll
                for (int dt = 0; dt < 4; dt++) {
                    const int d = dt * 16 + lc;
                    const int kvs = (f * 32 + lq * 8) ^ (((d >> 3) & 7) << 3);
                    bf16x8 bV = *(const bf16x8*)(vtb + d * 72 + kvs);
                    accO[dt] = __builtin_amdgcn_mfma_f32_16x16x32_bf16(bV, P.v, accO[dt], 0, 0, 0);
                }
                __builtin_amdgcn_s_setprio(0);
            }
        }

        // write next pair's V into the other buffer
        if (have) {
            short* dstb = &Vt[cur ^ 1][half][0];
#pragma unroll
            for (int i = 0; i < 8; i++) {
                u32 pk = ((u32)(unsigned short)nv0[i]) | (((u32)(unsigned short)nv1[i]) << 16);
                *(u32*)(dstb + (d0 + i) * 72 + kvs_w) = pk;
            }
        }
        __syncthreads();
    }

    // epilogue: ctx[b,h,q,d] = O^T[d][q] / l (fp32 to d_out, bf16 to ws)
    const float inv = 1.0f / lSum;
    const size_t rowoff = ((size_t)bh * SEQ + qbase + lc) * HDD;
    float* orow = ctxout + rowoff;
    short* brow = ctxb + rowoff;
#pragma unroll
    for (int dt = 0; dt < 4; dt++) {
        float4 st;
        st.x = accO[dt][0] * inv;
        st.y = accO[dt][1] * inv;
        st.z = accO[dt][2] * inv;
        st.w = accO[dt][3] * inv;
        *(float4*)(orow + dt * 16 + lq * 4) = st;
        uint2 bb;
        bb.x = ((u32)(unsigned short)f2bf(st.x)) | (((u32)(unsigned short)f2bf(st.y)) << 16);
        bb.y = ((u32)(unsigned short)f2bf(st.z)) | (((u32)(unsigned short)f2bf(st.w)) << 16);
        *(uint2*)(brow + dt * 16 + lq * 4) = bb;
    }
}

// ---------------------------------------------------------------------------
// Output projection: out = merged(ctx) @ Wo^T + bo. Both operands bf16.
// ---------------------------------------------------------------------------
__global__ __launch_bounds__(256) void outproj_kernel(
    const short* __restrict__ ctxb, const short* __restrict__ wob,
    const float* __restrict__ bo, float* __restrict__ out)
{
    const int m0 = blockIdx.x * 128;
    const int n0 = blockIdx.y * 128;
    const int tid = threadIdx.x;
    const int w = tid >> 6, lane = tid & 63, lc = lane & 15, lq = lane >> 4;
    const int wm = w >> 1, wn = w & 1;

    __shared__ alignas(16) short As[128 * 40];
    __shared__ alignas(16) short Bs[128 * 40];

    floatx4 acc[4][4];
#pragma unroll
    for (int i = 0; i < 4; i++)
#pragma unroll
        for (int j = 0; j < 4; j++) acc[i][j] = floatx4{0.f, 0.f, 0.f, 0.f};

    for (int kt = 0; kt < DM / 32; ++kt) {
        __syncthreads();
#pragma unroll
        for (int c = 0; c < 2; ++c) {
            int chunk = c * 256 + tid;
            int row = chunk >> 2;
            int col = (chunk & 3) * 8;
            int m = m0 + row;
            int b = m >> 11, s = m & 2047;
            int kcol = kt * 32 + col;
            int h = kcol >> 6, hd = kcol & 63;
            *(bf16x8*)(As + row * 40 + col) =
                *(const bf16x8*)(ctxb + (((size_t)(b * NH + h)) * SEQ + s) * HDD + hd);
            *(bf16x8*)(Bs + row * 40 + col) =
                *(const bf16x8*)(wob + (size_t)(n0 + row) * DM + kt * 32 + col);
        }
        __syncthreads();

        bf16x8 aF[4], bF[4];
#pragma unroll
        for (int i = 0; i < 4; i++)
            aF[i] = *(const bf16x8*)(As + (wm * 64 + i * 16 + lc) * 40 + lq * 8);
#pragma unroll
        for (int j = 0; j < 4; j++)
            bF[j] = *(const bf16x8*)(Bs + (wn * 64 + j * 16 + lc) * 40 + lq * 8);
        __builtin_amdgcn_s_setprio(1);
#pragma unroll
        for (int i = 0; i < 4; i++)
#pragma unroll
            for (int j = 0; j < 4; j++)
                acc[i][j] = __builtin_amdgcn_mfma_f32_16x16x32_bf16(aF[i], bF[j], acc[i][j], 0, 0, 0);
        __builtin_amdgcn_s_setprio(0);
    }

#pragma unroll
    for (int j = 0; j < 4; j++) {
        int n = n0 + wn * 64 + j * 16 + lc;
        float bias = bo[n];
#pragma unroll
        for (int i = 0; i < 4; i++) {
#pragma unroll
            for (int r = 0; r < 4; r++) {
                int m = m0 + wm * 64 + i * 16 + lq * 4 + r;
                out[(size_t)m * DM + n] = acc[i][j][r] + bias;
            }
        }
    }
}

extern "C" void kernel_launch(void* const* d_in, const int* in_sizes, int n_in,
                              void* d_out, int out_size, void* d_ws, size_t ws_size,
                              hipStream_t stream) {
    const float* q  = (const float*)d_in[0];
    const float* k  = (const float*)d_in[1];
    const float* v  = (const float*)d_in[2];
    const float* wq = (const float*)d_in[3];
    const float* bq = (const float*)d_in[4];
    const float* wk = (const float*)d_in[5];
    const float* bk = (const float*)d_in[6];
    const float* wv = (const float*)d_in[7];
    const float* bv = (const float*)d_in[8];
    const float* wo = (const float*)d_in[9];
    const float* bo = (const float*)d_in[10];

    float* out0 = (float*)d_out;                          // [B,S,D] fp32
    float* ctx  = out0 + (size_t)BB * SEQ * DM;           // [B,H,S,HD] fp32

    const size_t NELEM = (size_t)BB * NH * SEQ * HDD;     // 8.39M
    short* Qh   = (short*)d_ws;
    short* Kh   = Qh + NELEM;
    short* Vh   = Kh + NELEM;
    short* ctxb = Vh + NELEM;           // written by attn; until then holds Xv
    short* Wqb  = ctxb + NELEM;
    short* Wkb  = Wqb + (size_t)DM * DM;
    short* Wvb  = Wkb + (size_t)DM * DM;
    short* Wob  = Wvb + (size_t)DM * DM;
    // bf16 X: Xq/Xk borrow d_out's out0 region (written only by outproj at
    // the end); Xv aliases ctxb (written only by attn, after proj reads Xv).
    short* Xq = (short*)out0;
    short* Xk = Xq + NELEM;
    short* Xv = ctxb;
    // ws total: 4*NELEM + 4*DM*DM shorts = 75.5MB (same as prior round)

    conv_kernel<<<dim3(4096, 7), 256, 0, stream>>>(
        wq, wk, wv, wo, q, k, v, Wqb, Wkb, Wvb, Wob, Xq, Xk, Xv);
    proj_kernel<<<dim3(64, 8, 3), 256, 0, stream>>>(
        Xq, Xk, Xv, Wqb, bq, Wkb, bk, Wvb, bv, Qh, Kh, Vh);
    attn_kernel<<<dim3(16, 64), 512, 0, stream>>>(Qh, Kh, Vh, ctx, ctxb);
    outproj_kernel<<<dim3(64, 8), 256, 0, stream>>>(ctxb, Wob, bo, out0);
}